// Round 17
// baseline (387.471 us; speedup 1.0000x reference)
//
#include <hip/hip_runtime.h>
#include <hip/hip_bf16.h>
#include <math.h>

// Problem constants
#define NROWS 65536      // 32*2048
#define DDIM  768
#define KCODES 1024
#define NCB   8          // code blocks (KCODES / BK)
#define BM    128        // rows per block tile
#define BK    128        // codes per block tile
#define KC    32         // K-chunk for fallback kernel
#define NCH   (DDIM / KC)
#define BK2   32         // K-chunk (fp16) for gload_lds kernel
#define NCH2  (DDIM / BK2)
#define PANEL_USH (24 * 4096)   // ushorts per 128-row fp16 panel (24 chunks x 8KB)
#define GAP_TAU  0.3f    // fp16 score-error guard band (~7.5 sigma); near-ties re-checked in fp64
#define FILT_TAU 0.6f    // repair block-filter margin (2x guard band)
#define RGRID 2048       // k_repair blocks
#define QGRID 2048       // k_quantize blocks

// ---- output offsets (d_out is float32, outputs concatenated in return order)
#define OUT_LOSS ((size_t)NROWS * DDIM)
#define OUT_IDX  (OUT_LOSS + 1)
#define OUT_MIND (OUT_IDX + NROWS)
#define OUT_PERP (OUT_MIND + NROWS)

// ---- workspace offsets (bytes)
#define WS_SUM    0                              // double sum_sqerr
#define WS_NSUS   8                              // int n_suspect
#define WS_NVAL   12                             // unsigned n_valid
#define WS_COUNTS 256                            // float[KCODES]
#define WS_WSQ    (WS_COUNTS + 4*KCODES)         // float[KCODES]
#define WS_XSQ    (WS_WSQ + 4*KCODES)            // float[NROWS]  ||x||^2 per row
#define WS_ROWS   (WS_XSQ + 4*NROWS)             // float[NROWS] row min score (dist - xsq)
#define WS_ROWI   (WS_ROWS + 4*NROWS)            // int[NROWS] row argmin
#define WS_SUSP   (WS_ROWI + 4*NROWS)            // int[NROWS] suspect rows
#define WS_PM1    (WS_SUSP + 4*NROWS)            // float[NROWS*NCB] partial min
#define WS_PM2    (WS_PM1 + (size_t)4*NROWS*NCB) // float[NROWS*NCB] partial 2nd min
#define WS_PIDX   (WS_PM2 + (size_t)4*NROWS*NCB) // int[NROWS*NCB] partial argmin
#define WS_END    (WS_PIDX + (size_t)4*NROWS*NCB)
// fp16 mirrors (tiled LDS-image layout), used only if ws_size permits (~105 MB total)
#define WS_AF16   ((WS_END + 255) & ~(size_t)255)
#define WS_WF16   (WS_AF16 + (size_t)NROWS * DDIM * 2)
#define WS_END2   (WS_WF16 + (size_t)KCODES * DDIM * 2)

typedef __attribute__((ext_vector_type(8))) _Float16 half8;   // 8 f16 = 4 VGPRs (MFMA A/B frag)
typedef __attribute__((ext_vector_type(4))) float f32x4;      // NT-store vector / small acc
typedef __attribute__((ext_vector_type(16))) float f32x16;    // 32x32 MFMA C/D frag

// async global->LDS, 16B per lane; LDS dest = wave-uniform base + lane*16
#define GLOAD16(gsrc, ldst) \
    __builtin_amdgcn_global_load_lds( \
        (const __attribute__((address_space(1))) unsigned int*)(gsrc), \
        (__attribute__((address_space(3))) unsigned int*)(ldst), 16, 0, 0)

template <typename T>
__device__ inline T waveRedAdd(T v) {
#pragma unroll
    for (int o = 32; o; o >>= 1) v += __shfl_xor(v, o);
    return v;
}

__device__ inline ushort f2h(float f) {
    union { _Float16 h; ushort u; } c;
    c.h = (_Float16)f;   // RTN-even
    return c.u;
}

__device__ inline void nt_store4(float* p, float x, float y, float z, float w) {
    f32x4 v; v.x = x; v.y = y; v.z = z; v.w = w;
    __builtin_nontemporal_store(v, (f32x4*)p);   // clang vector type: accepted by the builtin
}

// ---------------------------------------------------------------- ||e_k||^2 (exact fp32) + fused init
__global__ __launch_bounds__(256) void k_wsq(const float* __restrict__ W, float* __restrict__ wsq,
                                             float* __restrict__ counts, int* __restrict__ n_suspect,
                                             unsigned* __restrict__ n_valid, double* __restrict__ sum_sqerr) {
    const int k = blockIdx.x;
    const int t = threadIdx.x;
    if (t == 0) {
        counts[k] = 0.f;
        if (k == 0) { *n_suspect = 0; *n_valid = 0u; *sum_sqerr = 0.0; }
    }
    const float* w = W + (size_t)k * DDIM;
    const float a = w[t], b = w[t + 256], c = w[t + 512];
    float s = a * a + b * b + c * c;
    s = waveRedAdd(s);
    __shared__ float p[4];
    if ((t & 63) == 0) p[t >> 6] = s;
    __syncthreads();
    if (t == 0) wsq[k] = (p[0] + p[1]) + (p[2] + p[3]);
}

// ---------------------------------------------------------------- ||x||^2 fallback (only if !big)
__global__ __launch_bounds__(256) void k_xsq(const float* __restrict__ A, float* __restrict__ xsq) {
    const int wid = threadIdx.x >> 6, lane = threadIdx.x & 63;
    const int row = blockIdx.x * 4 + wid;
    const float* x = A + (size_t)row * DDIM;
    float s = 0.f;
#pragma unroll
    for (int j = 0; j < 3; ++j) {
        const float4 v = *(const float4*)(x + (lane + 64 * j) * 4);
        s += v.x * v.x + v.y * v.y + v.z * v.z + v.w * v.w;
    }
    s = waveRedAdd(s);
    if (lane == 0) xsq[row] = s;
}

// ---------------------------------------------------------------- fp32 -> fp16 pre-convert (tiled LDS image) + fused xsq
#define ASLOTS (NROWS * (DDIM / 8))
#define TSLOTS ((NROWS + KCODES) * (DDIM / 8))
__global__ __launch_bounds__(192) void k_convert(
    const float* __restrict__ A, const float* __restrict__ W,
    ushort* __restrict__ Af16, ushort* __restrict__ Wf16,
    float* __restrict__ xsq)
{
    __shared__ float part[4];
    const int t = threadIdx.x;
    const int wv = t >> 6;   // wave 0,1,2

#pragma unroll 1
    for (size_t base = (size_t)blockIdx.x * 192; base < (size_t)TSLOTS; base += (size_t)gridDim.x * 192) {
        const size_t gidx = base + t;
        const bool isA = base < (size_t)ASLOTS;   // ASLOTS % 192 == 0 -> block-uniform region
        const float* src = isA ? A : W;
        ushort* dst = isA ? Af16 : Wf16;
        const int sid = (int)(gidx - (isA ? 0 : (size_t)ASLOTS));
        const int row = sid / 96;           // region-relative row
        const int sl = sid - row * 96;
        const int ch = sl >> 2, s = sl & 3; // 24 chunks x 4 slots of 16B
        const float* p = src + (size_t)row * DDIM + ch * 32 + s * 8;
        const float4 a = *(const float4*)p;
        const float4 b = *(const float4*)(p + 4);
        uint4 v;
        v.x = ((unsigned)f2h(a.y) << 16) | f2h(a.x);
        v.y = ((unsigned)f2h(a.w) << 16) | f2h(a.z);
        v.z = ((unsigned)f2h(b.y) << 16) | f2h(b.x);
        v.w = ((unsigned)f2h(b.w) << 16) | f2h(b.z);
        const size_t dsti = (size_t)(row >> 7) * PANEL_USH + ch * 4096
                          + (row & 127) * 32 + ((s ^ ((row >> 1) & 3)) << 3);
        *(uint4*)(dst + dsti) = v;

        if (isA) {
            // fused xsq: threads 0-95 = row r0 (base/96), 96-191 = r0+1
            float sq = a.x * a.x + a.y * a.y + a.z * a.z + a.w * a.w
                     + b.x * b.x + b.y * b.y + b.z * b.z + b.w * b.w;
            if (wv == 1) {   // wave 1 straddles the row boundary: reduce 32-lane halves
#pragma unroll
                for (int o = 16; o; o >>= 1) sq += __shfl_xor(sq, o);
            } else {
                sq = waveRedAdd(sq);
            }
            if (t == 0)   part[0] = sq;   // r0 slots 0-63
            if (t == 64)  part[1] = sq;   // r0 slots 64-95
            if (t == 96)  part[2] = sq;   // r1 slots 0-31
            if (t == 128) part[3] = sq;   // r1 slots 32-95
            __syncthreads();
            if (t == 0) {
                const int r0 = (int)(base / 96);
                xsq[r0]     = part[0] + part[1];
                xsq[r0 + 1] = part[2] + part[3];
            }
            __syncthreads();   // part[] reused next iteration
        }
    }
}

// ---------------------------------------------------------------- main GEMM (fp16 MFMA 32x32x16, tiled gload_lds, depth-2)
// Same proven schedule as r16 (counted vmcnt(4), dbuf, 4 blocks/CU) but with
// mfma_f32_32x32x16_f16: HALF the MFMA instruction count per chunk (8 vs 16), same
// FLOP, same conflict-free ds_read pattern (per-16-lane bank walk identical).
// A-frag: row=lane&31, k=(lane>>5)*8+j. C/D: col=lane&31, row=(reg&3)+8*(reg>>2)+4*(lane>>5).
__global__ __launch_bounds__(256, 4) void k_partials_g(
    const ushort* __restrict__ Af16, const ushort* __restrict__ Wf16,
    const float* __restrict__ wsq,
    float* __restrict__ pm1, float* __restrict__ pm2, int* __restrict__ pidx)
{
    __shared__ __align__(16) ushort lds[2 * 2 * BM * BK2];   // [buf][A|W][8KB] = 32 KB

    // XCD-panel swizzle: each XCD owns a contiguous band of 64 row-panels, cb fastest.
    const int bid = blockIdx.x;
    const int rb = ((bid & 7) << 6) | (bid >> 6);
    const int cb = (bid >> 3) & 7;

    const int tid = threadIdx.x;
    const int wid = tid >> 6, lane = tid & 63;
    const int wr = wid >> 1, wc = wid & 1;       // wave quadrant (row-half, col-half)
    const int l31 = lane & 31, h = lane >> 5;    // frag row/col (0..31) + k-group (0..1, 8 f16 each)

    const ushort* Ap = Af16 + (size_t)rb * PANEL_USH;   // tiled panel base
    const ushort* Wp = Wf16 + (size_t)cb * PANEL_USH;

    // within-buffer LDS read offsets (ushorts), loop-invariant
    // slot s = ks*2 + h (four 8-f16 slots per 32-k chunk row), swizzled by ((r>>1)&3)
    int aoff[2][2], boff[2][2];
#pragma unroll
    for (int mf = 0; mf < 2; ++mf) {
        const int r = wr * 64 + mf * 32 + l31;
#pragma unroll
        for (int ks = 0; ks < 2; ++ks)
            aoff[mf][ks] = r * 32 + (((ks * 2 + h) ^ ((r >> 1) & 3)) << 3);
    }
#pragma unroll
    for (int nf = 0; nf < 2; ++nf) {
        const int c = wc * 64 + nf * 32 + l31;
#pragma unroll
        for (int ks = 0; ks < 2; ++ks)
            boff[nf][ks] = c * 32 + (((ks * 2 + h) ^ ((c >> 1) & 3)) << 3);
    }

    f32x16 acc00 = (f32x16)0.f, acc01 = (f32x16)0.f;
    f32x16 acc10 = (f32x16)0.f, acc11 = (f32x16)0.f;

    const int lseg = lane << 3;   // lane*16B in ushorts
    auto STAGE = [&](int ch, int b) {   // 4 gloads/wave, 16 KB total per chunk
        ushort* As = lds + b * 8192;
        ushort* Ws = As + 4096;
        const ushort* Asrc = Ap + ch * 4096;
        const ushort* Wsrc = Wp + ch * 4096;
        GLOAD16(Asrc + (wid << 9) + lseg,       (char*)As + (wid << 10));
        GLOAD16(Asrc + ((wid + 4) << 9) + lseg, (char*)As + ((wid + 4) << 10));
        GLOAD16(Wsrc + (wid << 9) + lseg,       (char*)Ws + (wid << 10));
        GLOAD16(Wsrc + ((wid + 4) << 9) + lseg, (char*)Ws + ((wid + 4) << 10));
    };

    // prologue: chunks 0 and 1 in flight (8 loads/wave); wait only chunk 0 (vmcnt(4))
    STAGE(0, 0);
    STAGE(1, 1);
    asm volatile("s_waitcnt vmcnt(4)" ::: "memory");
    __builtin_amdgcn_s_barrier();

#pragma unroll 1
    for (int ch = 0; ch < NCH2; ++ch) {
        const int cur = ch & 1;
        const ushort* As = lds + cur * 8192;
        const ushort* Ws = As + 4096;
        const half8 b00 = *(const half8*)(Ws + boff[0][0]);
        const half8 b01 = *(const half8*)(Ws + boff[0][1]);
        const half8 b10 = *(const half8*)(Ws + boff[1][0]);
        const half8 b11 = *(const half8*)(Ws + boff[1][1]);
        const half8 a00 = *(const half8*)(As + aoff[0][0]);
        const half8 a01 = *(const half8*)(As + aoff[0][1]);
        const half8 a10 = *(const half8*)(As + aoff[1][0]);
        const half8 a11 = *(const half8*)(As + aoff[1][1]);
        __builtin_amdgcn_s_setprio(1);
        acc00 = __builtin_amdgcn_mfma_f32_32x32x16_f16(a00, b00, acc00, 0, 0, 0);
        acc00 = __builtin_amdgcn_mfma_f32_32x32x16_f16(a01, b01, acc00, 0, 0, 0);
        acc01 = __builtin_amdgcn_mfma_f32_32x32x16_f16(a00, b10, acc01, 0, 0, 0);
        acc01 = __builtin_amdgcn_mfma_f32_32x32x16_f16(a01, b11, acc01, 0, 0, 0);
        acc10 = __builtin_amdgcn_mfma_f32_32x32x16_f16(a10, b00, acc10, 0, 0, 0);
        acc10 = __builtin_amdgcn_mfma_f32_32x32x16_f16(a11, b01, acc10, 0, 0, 0);
        acc11 = __builtin_amdgcn_mfma_f32_32x32x16_f16(a10, b10, acc11, 0, 0, 0);
        acc11 = __builtin_amdgcn_mfma_f32_32x32x16_f16(a11, b11, acc11, 0, 0, 0);
        __builtin_amdgcn_s_setprio(0);
        if (ch + 1 == NCH2) break;
        asm volatile("s_waitcnt lgkmcnt(0)" ::: "memory");   // my reads of buf[cur] retired
        __builtin_amdgcn_s_barrier();                        // all waves' reads retired
        if (ch + 2 < NCH2) {
            STAGE(ch + 2, cur);                              // overwrite buf[cur] (safe now)
            asm volatile("s_waitcnt vmcnt(4)" ::: "memory"); // chunk ch+1 landed; ch+2 stays in flight
        } else {
            asm volatile("s_waitcnt vmcnt(0)" ::: "memory"); // tail: last chunk landed
        }
        __builtin_amdgcn_s_barrier();                        // visibility across waves
    }
    __syncthreads();   // drain + all waves done before LDS is reused as epilogue scratch

    // ---------------- epilogue: per-row (min, 2nd-min, argmin) over this 128-code tile
    // 32x32 C/D: code = cbase + nf*32 (col=lane&31); row = (reg&3)+8*(reg>>2)+4*h.
    const float wq0 = wsq[cb * BK + wc * 64 + l31];
    const float wq1 = wsq[cb * BK + wc * 64 + 32 + l31];
    const int code0 = cb * BK + wc * 64 + l31;
    const int code1 = code0 + 32;

    float* tm1 = (float*)lds;          // [128][2]  (row-local, wc)
    float* tm2 = tm1 + 256;
    int*   ti1 = (int*)(tm2 + 256);

    auto reduceFrag = [&](const f32x16& aN0, const f32x16& aN1, int mf) {
#pragma unroll
        for (int r = 0; r < 16; ++r) {
            const float s0 = fmaf(-2.f, aN0[r], wq0);
            const float s1 = fmaf(-2.f, aN1[r], wq1);
            float m1, m2; int i1;
            if (s1 < s0) { m1 = s1; i1 = code1; m2 = s0; }
            else         { m1 = s0; i1 = code0; m2 = s1; }   // tie -> smaller idx (code0)
#pragma unroll
            for (int msk = 1; msk <= 16; msk <<= 1) {        // reduce within 32-lane half
                const float om1 = __shfl_xor(m1, msk);
                const float om2 = __shfl_xor(m2, msk);
                const int   oi1 = __shfl_xor(i1, msk);
                if (om1 < m1 || (om1 == m1 && oi1 < i1)) { m2 = fminf(m1, om2); m1 = om1; i1 = oi1; }
                else m2 = fminf(m2, om1);
            }
            if (l31 == 0) {
                const int rl = wr * 64 + mf * 32 + (r & 3) + 8 * (r >> 2) + 4 * h;   // row within block
                tm1[rl * 2 + wc] = m1;
                tm2[rl * 2 + wc] = m2;
                ti1[rl * 2 + wc] = i1;
            }
        }
    };
    reduceFrag(acc00, acc01, 0);
    reduceFrag(acc10, acc11, 1);

    __syncthreads();
    if (tid < BM) {
        float m1 = tm1[tid * 2], m2 = tm2[tid * 2]; int i1 = ti1[tid * 2];
        const float bm1 = tm1[tid * 2 + 1], bm2 = tm2[tid * 2 + 1]; const int bi = ti1[tid * 2 + 1];
        if (bm1 < m1 || (bm1 == m1 && bi < i1)) { m2 = fminf(m1, bm2); m1 = bm1; i1 = bi; }
        else m2 = fminf(m2, bm1);
        const size_t row = (size_t)rb * BM + tid;
        pm1[row * NCB + cb] = m1;
        pm2[row * NCB + cb] = m2;
        pidx[row * NCB + cb] = i1;
    }
}

// ---------------------------------------------------------------- fallback GEMM (fused cvt) if ws too small
__global__ __launch_bounds__(256, 2) void k_partials(
    const float* __restrict__ A, const float* __restrict__ W,
    const float* __restrict__ wsq,
    float* __restrict__ pm1, float* __restrict__ pm2, int* __restrict__ pidx)
{
    __shared__ __align__(16) ushort lds[2 * BM * KC];
    ushort* As = lds;
    ushort* Ws = lds + BM * KC;

    const int bid = blockIdx.x;
    const int rb = ((bid & 7) << 6) | (bid >> 6);
    const int cb = (bid >> 3) & 7;

    const int tid = threadIdx.x;
    const int wid = tid >> 6, lane = tid & 63;
    const int wr = wid >> 1, wc = wid & 1;
    const int l15 = lane & 15, g = lane >> 4;

    const float* Ab = A + (size_t)rb * BM * DDIM;
    const float* Wb = W + (size_t)cb * BK * DDIM;

    const int srow = tid >> 3;
    const int sk4  = (tid & 7) << 2;
    const int sg   = (tid & 7) >> 1;
    const int sh   = (tid & 1) << 2;

    int aOff[4], bOff[4];
#pragma unroll
    for (int rt = 0; rt < 4; ++rt) {
        const int r = wr * 64 + rt * 16 + l15;
        aOff[rt] = r * KC + ((g ^ ((r >> 1) & 3)) << 3);
        const int c = wc * 64 + rt * 16 + l15;
        bOff[rt] = c * KC + ((g ^ ((c >> 1) & 3)) << 3);
    }

    f32x4 acc[4][4];
#pragma unroll
    for (int rt = 0; rt < 4; ++rt)
#pragma unroll
        for (int ct = 0; ct < 4; ++ct) acc[rt][ct] = (f32x4)0.f;

    float4 av[4], wv[4];
#pragma unroll
    for (int i = 0; i < 4; ++i) {
        av[i] = *(const float4*)(Ab + (size_t)(srow + 32 * i) * DDIM + sk4);
        wv[i] = *(const float4*)(Wb + (size_t)(srow + 32 * i) * DDIM + sk4);
    }

#pragma unroll 1
    for (int ch = 0; ch < NCH; ++ch) {
        __syncthreads();
#pragma unroll
        for (int i = 0; i < 4; ++i) {
            const int r = srow + 32 * i;
            const int wsl = r * KC + ((sg ^ ((r >> 1) & 3)) << 3) + sh;
            ushort4 ua; ua.x = f2h(av[i].x); ua.y = f2h(av[i].y); ua.z = f2h(av[i].z); ua.w = f2h(av[i].w);
            *(ushort4*)(As + wsl) = ua;
            ushort4 uw; uw.x = f2h(wv[i].x); uw.y = f2h(wv[i].y); uw.z = f2h(wv[i].z); uw.w = f2h(wv[i].w);
            *(ushort4*)(Ws + wsl) = uw;
        }
        __syncthreads();
        if (ch + 1 < NCH) {
            const int d0 = (ch + 1) * KC + sk4;
#pragma unroll
            for (int i = 0; i < 4; ++i) {
                av[i] = *(const float4*)(Ab + (size_t)(srow + 32 * i) * DDIM + d0);
                wv[i] = *(const float4*)(Wb + (size_t)(srow + 32 * i) * DDIM + d0);
            }
        }
        half8 af[4], bf[4];
#pragma unroll
        for (int rt = 0; rt < 4; ++rt) af[rt] = *(const half8*)(As + aOff[rt]);
#pragma unroll
        for (int ct = 0; ct < 4; ++ct) bf[ct] = *(const half8*)(Ws + bOff[ct]);
#pragma unroll
        for (int rt = 0; rt < 4; ++rt)
#pragma unroll
            for (int ct = 0; ct < 4; ++ct)
                acc[rt][ct] = __builtin_amdgcn_mfma_f32_16x16x32_f16(af[rt], bf[ct], acc[rt][ct], 0, 0, 0);
    }

    float wq[4];
#pragma unroll
    for (int ct = 0; ct < 4; ++ct) wq[ct] = wsq[cb * BK + wc * 64 + ct * 16 + l15];
    const int cbase = cb * BK + wc * 64 + l15;

    __syncthreads();
    float* tm1 = (float*)lds;
    float* tm2 = tm1 + 256;
    int*   ti1 = (int*)(tm2 + 256);

#pragma unroll
    for (int rt = 0; rt < 4; ++rt) {
        float m1q[4], m2q[4]; int i1q[4];
#pragma unroll
        for (int q = 0; q < 4; ++q) { m1q[q] = INFINITY; m2q[q] = INFINITY; i1q[q] = 0x7fffffff; }
#pragma unroll
        for (int ct = 0; ct < 4; ++ct) {
            const int col = cbase + ct * 16;
#pragma unroll
            for (int q = 0; q < 4; ++q) {
                const float s = fmaf(-2.f, acc[rt][ct][q], wq[ct]);
                if (s < m1q[q]) { m2q[q] = m1q[q]; m1q[q] = s; i1q[q] = col; }
                else if (s < m2q[q]) m2q[q] = s;
            }
        }
#pragma unroll
        for (int msk = 1; msk <= 8; msk <<= 1) {
#pragma unroll
            for (int q = 0; q < 4; ++q) {
                const float om1 = __shfl_xor(m1q[q], msk);
                const float om2 = __shfl_xor(m2q[q], msk);
                const int   oi1 = __shfl_xor(i1q[q], msk);
                if (om1 < m1q[q] || (om1 == m1q[q] && oi1 < i1q[q])) {
                    m2q[q] = fminf(m1q[q], om2); m1q[q] = om1; i1q[q] = oi1;
                } else m2q[q] = fminf(m2q[q], om1);
            }
        }
        if (l15 == 0) {
#pragma unroll
            for (int q = 0; q < 4; ++q) {
                const int rl = wr * 64 + rt * 16 + g * 4 + q;
                tm1[rl * 2 + wc] = m1q[q];
                tm2[rl * 2 + wc] = m2q[q];
                ti1[rl * 2 + wc] = i1q[q];
            }
        }
    }
    __syncthreads();
    if (tid < BM) {
        float m1 = tm1[tid * 2], m2 = tm2[tid * 2]; int i1 = ti1[tid * 2];
        const float bm1 = tm1[tid * 2 + 1], bm2 = tm2[tid * 2 + 1]; const int bi = ti1[tid * 2 + 1];
        if (bm1 < m1 || (bm1 == m1 && bi < i1)) { m2 = fminf(m1, bm2); m1 = bm1; i1 = bi; }
        else m2 = fminf(m2, bm1);
        const size_t row = (size_t)rb * BM + tid;
        pm1[row * NCB + cb] = m1;
        pm2[row * NCB + cb] = m2;
        pidx[row * NCB + cb] = i1;
    }
}

// ---------------------------------------------------------------- merge 8 partials per row
__global__ __launch_bounds__(256) void k_merge(
    const float* __restrict__ pm1, const float* __restrict__ pm2, const int* __restrict__ pidx,
    float* __restrict__ row_s, int* __restrict__ row_idx,
    int* __restrict__ suspects, int* __restrict__ n_suspect)
{
    const int row = blockIdx.x * 256 + threadIdx.x;
    float m1 = INFINITY, m2 = INFINITY; int i1 = 0x7fffffff;
#pragma unroll
    for (int cb = 0; cb < NCB; ++cb) {
        const float bm1 = pm1[(size_t)row * NCB + cb];
        const float bm2 = pm2[(size_t)row * NCB + cb];
        const int   bi  = pidx[(size_t)row * NCB + cb];
        if (bm1 < m1 || (bm1 == m1 && bi < i1)) { m2 = fminf(m1, bm2); m1 = bm1; i1 = bi; }
        else m2 = fminf(m2, bm1);
    }
    row_s[row] = m1;
    row_idx[row] = i1;
    if (m2 - m1 < GAP_TAU) {   // fp16 noise could have reordered: exact re-check
        const int p = atomicAdd(n_suspect, 1);
        suspects[p] = row;
    }
}

// ---------------------------------------------------------------- fp64 re-check of near-ties
__global__ __launch_bounds__(256) void k_repair(
    const float* __restrict__ A, const float* __restrict__ W,
    const float* __restrict__ pm1,
    const int* __restrict__ suspects, const int* __restrict__ n_suspect,
    float* __restrict__ row_s, int* __restrict__ row_idx)
{
    __shared__ __align__(16) float xrow[DDIM];
    __shared__ double wbest[4]; __shared__ int wbi[4];
    __shared__ double xps[4];
    __shared__ int qcb[NCB];
    __shared__ int nq;
    const int ns = *n_suspect;
    const int tid = threadIdx.x;
    const int wid = tid >> 6, lane = tid & 63;
    const int sub = tid & 3;        // 16B stripe within a code
    const int cq  = tid >> 2;       // code slot 0..63

    for (int s = blockIdx.x; s < ns; s += gridDim.x) {
        const int row = suspects[s];
        __syncthreads();   // previous iteration done with shared
        xrow[tid]       = A[(size_t)row * DDIM + tid];
        xrow[tid + 256] = A[(size_t)row * DDIM + tid + 256];
        xrow[tid + 512] = A[(size_t)row * DDIM + tid + 512];
        if (tid == 0) {
            float gmin = INFINITY;
#pragma unroll
            for (int cb = 0; cb < NCB; ++cb) gmin = fminf(gmin, pm1[(size_t)row * NCB + cb]);
            int n = 0;
#pragma unroll
            for (int cb = 0; cb < NCB; ++cb)
                if (pm1[(size_t)row * NCB + cb] <= gmin + FILT_TAU) qcb[n++] = cb;
            nq = n;
        }
        __syncthreads();

        // xsq in fp64 (per-wave stripes combined at the end)
        double xp = 0.0;
        {
            double t;
            t = (double)xrow[tid];       xp = fma(t, t, xp);
            t = (double)xrow[tid + 256]; xp = fma(t, t, xp);
            t = (double)xrow[tid + 512]; xp = fma(t, t, xp);
        }
        xp = waveRedAdd(xp);
        if (lane == 0) xps[wid] = xp;

        double best = 1e300; int bi = 0x7fffffff;
        const int ncand = nq * BK;
        for (int base = 0; base < ncand; base += 64) {
            const int ci = base + cq;
            const bool act = ci < ncand;       // uniform within a quad
            double d = 0.0; int k = 0x7fffffff;
            if (act) {
                k = qcb[ci >> 7] * BK + (ci & (BK - 1));
                const float* wr = W + (size_t)k * DDIM + (sub << 2);
                const float* xr = xrow + (sub << 2);
                double d0 = 0.0, d1 = 0.0;
                for (int i = 0; i < DDIM; i += 16) {
                    const float4 wv = *(const float4*)(wr + i);
                    const float4 xv = *(const float4*)(xr + i);
                    double t;
                    t = (double)xv.x - (double)wv.x; d0 = fma(t, t, d0);
                    t = (double)xv.y - (double)wv.y; d1 = fma(t, t, d1);
                    t = (double)xv.z - (double)wv.z; d0 = fma(t, t, d0);
                    t = (double)xv.w - (double)wv.w; d1 = fma(t, t, d1);
                }
                d = d0 + d1;
            }
            d += __shfl_xor(d, 1);   // combine the 4 stripes of this code
            d += __shfl_xor(d, 2);
            if (act && sub == 0) {
                if (d < best || (d == best && k < bi)) { best = d; bi = k; }
            }
        }
        // wave butterfly (non-leaders hold +inf)
#pragma unroll
        for (int o = 32; o; o >>= 1) {
            const double ob = __shfl_xor(best, o);
            const int oi = __shfl_xor(bi, o);
            if (ob < best || (ob == best && oi < bi)) { best = ob; bi = oi; }
        }
        if (lane == 0) { wbest[wid] = best; wbi[wid] = bi; }
        __syncthreads();
        if (tid == 0) {
            double b = wbest[0]; int i1 = wbi[0];
#pragma unroll
            for (int w = 1; w < 4; ++w)
                if (wbest[w] < b || (wbest[w] == b && wbi[w] < i1)) { b = wbest[w]; i1 = wbi[w]; }
            row_idx[row] = i1;
            row_s[row] = (float)(b - (xps[0] + xps[1] + xps[2] + xps[3]));   // score form (dist - xsq)
        }
    }
}

// ---------------------------------------------------------------- quantize + losses + idx/min_d outputs
__global__ __launch_bounds__(256) void k_quantize(
    const float* __restrict__ W,
    const float* __restrict__ xsq,
    const float* __restrict__ row_s, const int* __restrict__ row_idx,
    float* __restrict__ out, float* __restrict__ counts,
    unsigned int* __restrict__ n_valid, double* __restrict__ sum_sqerr)
{
    const int wid = threadIdx.x >> 6, lane = threadIdx.x & 63;
    __shared__ double s_sum[4];
    __shared__ unsigned s_val[4];
    double wsum = 0.0; unsigned wval = 0;

#pragma unroll 1
    for (int it = 0; it < NROWS / (QGRID * 4); ++it) {
        const int row = (it * QGRID + blockIdx.x) * 4 + wid;
        const float xs = xsq[row];
        const bool valid = xs > 1e-12f;            // norm > 1e-6
        const int idx = row_idx[row];
        const int idxm = valid ? idx : 0;
        const float maskf = valid ? 1.f : 0.f;
        const float* w = W + (size_t)idx * DDIM;
        float* oq = out + (size_t)row * DDIM;
#pragma unroll
        for (int j = 0; j < 3; ++j) {
            const float4 wv = *(const float4*)(w + (lane + 64 * j) * 4);
            nt_store4(oq + (lane + 64 * j) * 4,
                      wv.x * maskf, wv.y * maskf, wv.z * maskf, wv.w * maskf);
        }
        if (lane == 0) {
            const float mind = xs + row_s[row];
            if (valid) {
                wsum += (double)mind;
                ++wval;
                atomicAdd(&counts[idxm], 1.0f);
            }
            out[OUT_IDX + row]  = (float)idxm;
            out[OUT_MIND + row] = valid ? mind : 0.f;
        }
    }

    if (lane == 0) { s_sum[wid] = wsum; s_val[wid] = wval; }
    __syncthreads();
    if (threadIdx.x == 0) {
        atomicAdd(sum_sqerr, s_sum[0] + s_sum[1] + s_sum[2] + s_sum[3]);
        atomicAdd(n_valid, s_val[0] + s_val[1] + s_val[2] + s_val[3]);
    }
}

// ---------------------------------------------------------------- scalar losses
__global__ __launch_bounds__(256) void k_final(
    const float* __restrict__ counts, const unsigned int* __restrict__ n_valid,
    const double* __restrict__ sum_sqerr, float* __restrict__ out)
{
    const int t = threadIdx.x;
    const float nv = (float)(*n_valid);
    double ent = 0.0;
    for (int k = t; k < KCODES; k += 256) {
        const float p = counts[k] / nv;
        ent += (double)(p * logf(p + 1e-10f));
    }
    ent = waveRedAdd(ent);
    __shared__ double ps[4];
    if ((t & 63) == 0) ps[t >> 6] = ent;
    __syncthreads();
    if (t == 0) {
        const double e = ps[0] + ps[1] + ps[2] + ps[3];
        const double perp = exp(-e);
        const double ploss = -log(perp + 1e-10);
        const double commit = *sum_sqerr / ((double)(*n_valid) * (double)DDIM);
        out[OUT_LOSS] = (float)(0.25 * commit + 0.1 * ploss);
        out[OUT_PERP] = (float)perp;
    }
}

// ----------------------------------------------------------------
extern "C" void kernel_launch(void* const* d_in, const int* in_sizes, int n_in,
                              void* d_out, int out_size, void* d_ws, size_t ws_size,
                              hipStream_t stream) {
    const float* A = (const float*)d_in[0];   // [65536, 768]
    const float* W = (const float*)d_in[1];   // [1024, 768]
    float* out = (float*)d_out;
    char* ws = (char*)d_ws;
    if (ws_size < (size_t)WS_END) return;     // needs >=7 MB scratch

    double*   sum_sqerr = (double*)(ws + WS_SUM);
    int*      n_suspect = (int*)(ws + WS_NSUS);
    unsigned* n_valid   = (unsigned*)(ws + WS_NVAL);
    float*    counts    = (float*)(ws + WS_COUNTS);
    float*    wsq       = (float*)(ws + WS_WSQ);
    float*    xsq       = (float*)(ws + WS_XSQ);
    float*    row_s     = (float*)(ws + WS_ROWS);
    int*      row_idx   = (int*)(ws + WS_ROWI);
    int*      suspects  = (int*)(ws + WS_SUSP);
    float*    pm1       = (float*)(ws + WS_PM1);
    float*    pm2       = (float*)(ws + WS_PM2);
    int*      pidx      = (int*)(ws + WS_PIDX);
    ushort*   Af16      = (ushort*)(ws + WS_AF16);
    ushort*   Wf16      = (ushort*)(ws + WS_WF16);

    const bool big = ws_size >= (size_t)WS_END2;   // ~105 MB: fp16-preconvert path

    hipLaunchKernelGGL(k_wsq, dim3(KCODES), dim3(256), 0, stream, W, wsq, counts, n_suspect, n_valid, sum_sqerr);
    if (big) {
        hipLaunchKernelGGL(k_convert, dim3(2048), dim3(192), 0, stream, A, W, Af16, Wf16, xsq);
        hipLaunchKernelGGL(k_partials_g, dim3((NROWS / BM) * NCB), dim3(256), 0, stream, Af16, Wf16, wsq, pm1, pm2, pidx);
    } else {
        hipLaunchKernelGGL(k_xsq, dim3(NROWS / 4), dim3(256), 0, stream, A, xsq);
        hipLaunchKernelGGL(k_partials, dim3((NROWS / BM) * NCB), dim3(256), 0, stream, A, W, wsq, pm1, pm2, pidx);
    }
    hipLaunchKernelGGL(k_merge, dim3(NROWS / 256), dim3(256), 0, stream, pm1, pm2, pidx, row_s, row_idx, suspects, n_suspect);
    hipLaunchKernelGGL(k_repair, dim3(RGRID), dim3(256), 0, stream, A, W, pm1, suspects, n_suspect, row_s, row_idx);
    hipLaunchKernelGGL(k_quantize, dim3(QGRID), dim3(256), 0, stream, W, xsq, row_s, row_idx, out, counts, n_valid, sum_sqerr);
    hipLaunchKernelGGL(k_final, dim3(1), dim3(256), 0, stream, counts, n_valid, sum_sqerr, out);
}

// Round 18
// 340.251 us; speedup vs baseline: 1.1388x; 1.1388x over previous
//
#include <hip/hip_runtime.h>
#include <hip/hip_bf16.h>
#include <math.h>

// Problem constants
#define NROWS 65536      // 32*2048
#define DDIM  768
#define KCODES 1024
#define NCB   8          // code blocks (KCODES / BK)
#define BM    128        // rows per block tile
#define BK    128        // codes per block tile
#define KC    32         // K-chunk for fallback kernel
#define NCH   (DDIM / KC)
#define BK2   32         // K-chunk (fp16) for gload_lds kernel
#define NCH2  (DDIM / BK2)
#define PANEL_USH (24 * 4096)   // ushorts per 128-row fp16 panel (24 chunks x 8KB)
#define GAP_TAU  0.3f    // fp16 score-error guard band (~7.5 sigma); near-ties re-checked in fp64
#define FILT_TAU 0.6f    // repair block-filter margin (2x guard band)
#define RGRID 2048       // k_repair blocks
#define QGRID 2048       // k_quantize blocks

// ---- output offsets (d_out is float32, outputs concatenated in return order)
#define OUT_LOSS ((size_t)NROWS * DDIM)
#define OUT_IDX  (OUT_LOSS + 1)
#define OUT_MIND (OUT_IDX + NROWS)
#define OUT_PERP (OUT_MIND + NROWS)

// ---- workspace offsets (bytes)
#define WS_SUM    0                              // double sum_sqerr
#define WS_NSUS   8                              // int n_suspect
#define WS_NVAL   12                             // unsigned n_valid
#define WS_COUNTS 256                            // float[KCODES]
#define WS_WSQ    (WS_COUNTS + 4*KCODES)         // float[KCODES]
#define WS_XSQ    (WS_WSQ + 4*KCODES)            // float[NROWS]  ||x||^2 per row
#define WS_ROWS   (WS_XSQ + 4*NROWS)             // float[NROWS] row min score (dist - xsq)
#define WS_ROWI   (WS_ROWS + 4*NROWS)            // int[NROWS] row argmin
#define WS_SUSP   (WS_ROWI + 4*NROWS)            // int[NROWS] suspect rows
#define WS_PM1    (WS_SUSP + 4*NROWS)            // float[NROWS*NCB] partial min
#define WS_PM2    (WS_PM1 + (size_t)4*NROWS*NCB) // float[NROWS*NCB] partial 2nd min
#define WS_PIDX   (WS_PM2 + (size_t)4*NROWS*NCB) // int[NROWS*NCB] partial argmin
#define WS_END    (WS_PIDX + (size_t)4*NROWS*NCB)
// fp16 mirrors (tiled LDS-image layout), used only if ws_size permits (~105 MB total)
#define WS_AF16   ((WS_END + 255) & ~(size_t)255)
#define WS_WF16   (WS_AF16 + (size_t)NROWS * DDIM * 2)
#define WS_END2   (WS_WF16 + (size_t)KCODES * DDIM * 2)

typedef __attribute__((ext_vector_type(8))) _Float16 half8;  // 8 f16 = 4 VGPRs (MFMA A/B frag)
typedef __attribute__((ext_vector_type(4))) float f32x4;     // MFMA C/D frag / NT-store vector

// async global->LDS, 16B per lane; LDS dest = wave-uniform base + lane*16
#define GLOAD16(gsrc, ldst) \
    __builtin_amdgcn_global_load_lds( \
        (const __attribute__((address_space(1))) unsigned int*)(gsrc), \
        (__attribute__((address_space(3))) unsigned int*)(ldst), 16, 0, 0)

template <typename T>
__device__ inline T waveRedAdd(T v) {
#pragma unroll
    for (int o = 32; o; o >>= 1) v += __shfl_xor(v, o);
    return v;
}

__device__ inline ushort f2h(float f) {
    union { _Float16 h; ushort u; } c;
    c.h = (_Float16)f;   // RTN-even
    return c.u;
}

__device__ inline void nt_store4(float* p, float x, float y, float z, float w) {
    f32x4 v; v.x = x; v.y = y; v.z = z; v.w = w;
    __builtin_nontemporal_store(v, (f32x4*)p);   // clang vector type: accepted by the builtin
}

// ---------------------------------------------------------------- ||e_k||^2 (exact fp32) + fused init
__global__ __launch_bounds__(256) void k_wsq(const float* __restrict__ W, float* __restrict__ wsq,
                                             float* __restrict__ counts, int* __restrict__ n_suspect,
                                             unsigned* __restrict__ n_valid, double* __restrict__ sum_sqerr) {
    const int k = blockIdx.x;
    const int t = threadIdx.x;
    if (t == 0) {
        counts[k] = 0.f;
        if (k == 0) { *n_suspect = 0; *n_valid = 0u; *sum_sqerr = 0.0; }
    }
    const float* w = W + (size_t)k * DDIM;
    const float a = w[t], b = w[t + 256], c = w[t + 512];
    float s = a * a + b * b + c * c;
    s = waveRedAdd(s);
    __shared__ float p[4];
    if ((t & 63) == 0) p[t >> 6] = s;
    __syncthreads();
    if (t == 0) wsq[k] = (p[0] + p[1]) + (p[2] + p[3]);
}

// ---------------------------------------------------------------- ||x||^2 fallback (only if !big)
__global__ __launch_bounds__(256) void k_xsq(const float* __restrict__ A, float* __restrict__ xsq) {
    const int wid = threadIdx.x >> 6, lane = threadIdx.x & 63;
    const int row = blockIdx.x * 4 + wid;
    const float* x = A + (size_t)row * DDIM;
    float s = 0.f;
#pragma unroll
    for (int j = 0; j < 3; ++j) {
        const float4 v = *(const float4*)(x + (lane + 64 * j) * 4);
        s += v.x * v.x + v.y * v.y + v.z * v.z + v.w * v.w;
    }
    s = waveRedAdd(s);
    if (lane == 0) xsq[row] = s;
}

// ---------------------------------------------------------------- fp32 -> fp16 pre-convert (tiled LDS image) + fused xsq
// Output layout: panel (128 rows) x chunk (32 k) = contiguous 8 KB block laid out EXACTLY
// as the GEMM's LDS tile: ushort index = panel*PANEL_USH + ch*4096 + r_local*32 +
// (s ^ ((r>>1)&3))*8 (rule #21: source permutation == read permutation).
// 192-thread blocks = exactly 2 rows (96 slots each) -> segmented per-row xsq reduction.
#define ASLOTS (NROWS * (DDIM / 8))
#define TSLOTS ((NROWS + KCODES) * (DDIM / 8))
__global__ __launch_bounds__(192) void k_convert(
    const float* __restrict__ A, const float* __restrict__ W,
    ushort* __restrict__ Af16, ushort* __restrict__ Wf16,
    float* __restrict__ xsq)
{
    __shared__ float part[4];
    const int t = threadIdx.x;
    const int wv = t >> 6;   // wave 0,1,2

#pragma unroll 1
    for (size_t base = (size_t)blockIdx.x * 192; base < (size_t)TSLOTS; base += (size_t)gridDim.x * 192) {
        const size_t gidx = base + t;
        const bool isA = base < (size_t)ASLOTS;   // ASLOTS % 192 == 0 -> block-uniform region
        const float* src = isA ? A : W;
        ushort* dst = isA ? Af16 : Wf16;
        const int sid = (int)(gidx - (isA ? 0 : (size_t)ASLOTS));
        const int row = sid / 96;           // region-relative row
        const int sl = sid - row * 96;
        const int ch = sl >> 2, s = sl & 3; // 24 chunks x 4 slots of 16B
        const float* p = src + (size_t)row * DDIM + ch * 32 + s * 8;
        const float4 a = *(const float4*)p;
        const float4 b = *(const float4*)(p + 4);
        uint4 v;
        v.x = ((unsigned)f2h(a.y) << 16) | f2h(a.x);
        v.y = ((unsigned)f2h(a.w) << 16) | f2h(a.z);
        v.z = ((unsigned)f2h(b.y) << 16) | f2h(b.x);
        v.w = ((unsigned)f2h(b.w) << 16) | f2h(b.z);
        const size_t dsti = (size_t)(row >> 7) * PANEL_USH + ch * 4096
                          + (row & 127) * 32 + ((s ^ ((row >> 1) & 3)) << 3);
        *(uint4*)(dst + dsti) = v;

        if (isA) {
            // fused xsq: threads 0-95 = row r0 (base/96), 96-191 = r0+1
            float sq = a.x * a.x + a.y * a.y + a.z * a.z + a.w * a.w
                     + b.x * b.x + b.y * b.y + b.z * b.z + b.w * b.w;
            if (wv == 1) {   // wave 1 straddles the row boundary: reduce 32-lane halves
#pragma unroll
                for (int o = 16; o; o >>= 1) sq += __shfl_xor(sq, o);
            } else {
                sq = waveRedAdd(sq);
            }
            if (t == 0)   part[0] = sq;   // r0 slots 0-63
            if (t == 64)  part[1] = sq;   // r0 slots 64-95
            if (t == 96)  part[2] = sq;   // r1 slots 0-31
            if (t == 128) part[3] = sq;   // r1 slots 32-95
            __syncthreads();
            if (t == 0) {
                const int r0 = (int)(base / 96);
                xsq[r0]     = part[0] + part[1];
                xsq[r0 + 1] = part[2] + part[3];
            }
            __syncthreads();   // part[] reused next iteration
        }
    }
}

// ---------------------------------------------------------------- main GEMM (fp16 MFMA 16x16x32, tiled gload_lds, depth-2)
// r16 best-measured configuration (341 us total; partials 165 us, 0 bank conflicts).
// NOTE: 32x32 MFMA variant tried and REVERTED (r17): 64B-row LDS image has only 8
// bank-position classes; 32-lane fragment reads alias 4-way (1.26e7 conflicts, +40%).
// 16x16 spreads 16 lanes over those 8 classes -> 2-way = free (m136).
__global__ __launch_bounds__(256, 4) void k_partials_g(
    const ushort* __restrict__ Af16, const ushort* __restrict__ Wf16,
    const float* __restrict__ wsq,
    float* __restrict__ pm1, float* __restrict__ pm2, int* __restrict__ pidx)
{
    __shared__ __align__(16) ushort lds[2 * 2 * BM * BK2];   // [buf][A|W][8KB] = 32 KB

    // XCD-panel swizzle: each XCD owns a contiguous band of 64 row-panels, cb fastest.
    const int bid = blockIdx.x;
    const int rb = ((bid & 7) << 6) | (bid >> 6);
    const int cb = (bid >> 3) & 7;

    const int tid = threadIdx.x;
    const int wid = tid >> 6, lane = tid & 63;
    const int wr = wid >> 1, wc = wid & 1;       // wave quadrant (row-half, col-half)
    const int l15 = lane & 15, g = lane >> 4;    // frag row/col + k-group (0..3, 8 f16 each)

    const ushort* Ap = Af16 + (size_t)rb * PANEL_USH;   // tiled panel base
    const ushort* Wp = Wf16 + (size_t)cb * PANEL_USH;

    // within-buffer LDS read offsets (ushorts), loop-invariant
    int aoff[4], boff[4];
#pragma unroll
    for (int rt = 0; rt < 4; ++rt) {
        const int r = wr * 64 + rt * 16 + l15;
        aoff[rt] = r * 32 + ((g ^ ((r >> 1) & 3)) << 3);
        const int c = wc * 64 + rt * 16 + l15;
        boff[rt] = c * 32 + ((g ^ ((c >> 1) & 3)) << 3);
    }

    f32x4 acc[4][4];
#pragma unroll
    for (int rt = 0; rt < 4; ++rt)
#pragma unroll
        for (int ct = 0; ct < 4; ++ct) acc[rt][ct] = (f32x4)0.f;

    const int lseg = lane << 3;   // lane*16B in ushorts
    auto STAGE = [&](int ch, int b) {   // 4 gloads/wave, 16 KB total per chunk
        ushort* As = lds + b * 8192;
        ushort* Ws = As + 4096;
        const ushort* Asrc = Ap + ch * 4096;
        const ushort* Wsrc = Wp + ch * 4096;
        GLOAD16(Asrc + (wid << 9) + lseg,       (char*)As + (wid << 10));
        GLOAD16(Asrc + ((wid + 4) << 9) + lseg, (char*)As + ((wid + 4) << 10));
        GLOAD16(Wsrc + (wid << 9) + lseg,       (char*)Ws + (wid << 10));
        GLOAD16(Wsrc + ((wid + 4) << 9) + lseg, (char*)Ws + ((wid + 4) << 10));
    };

    // prologue: chunks 0 and 1 in flight (8 loads/wave); wait only chunk 0 (vmcnt(4))
    STAGE(0, 0);
    STAGE(1, 1);
    asm volatile("s_waitcnt vmcnt(4)" ::: "memory");
    __builtin_amdgcn_s_barrier();

#pragma unroll 1
    for (int ch = 0; ch < NCH2; ++ch) {
        const int cur = ch & 1;
        const ushort* As = lds + cur * 8192;
        const ushort* Ws = As + 4096;
        half8 bf[4];
#pragma unroll
        for (int ct = 0; ct < 4; ++ct) bf[ct] = *(const half8*)(Ws + boff[ct]);
        __builtin_amdgcn_s_setprio(1);
#pragma unroll
        for (int rt = 0; rt < 4; ++rt) {
            const half8 af = *(const half8*)(As + aoff[rt]);
#pragma unroll
            for (int ct = 0; ct < 4; ++ct)
                acc[rt][ct] = __builtin_amdgcn_mfma_f32_16x16x32_f16(af, bf[ct], acc[rt][ct], 0, 0, 0);
        }
        __builtin_amdgcn_s_setprio(0);
        if (ch + 1 == NCH2) break;
        asm volatile("s_waitcnt lgkmcnt(0)" ::: "memory");   // my reads of buf[cur] retired
        __builtin_amdgcn_s_barrier();                        // all waves' reads retired
        if (ch + 2 < NCH2) {
            STAGE(ch + 2, cur);                              // overwrite buf[cur] (safe now)
            asm volatile("s_waitcnt vmcnt(4)" ::: "memory"); // chunk ch+1 landed; ch+2 stays in flight
        } else {
            asm volatile("s_waitcnt vmcnt(0)" ::: "memory"); // tail: last chunk landed
        }
        __builtin_amdgcn_s_barrier();                        // visibility across waves
    }
    __syncthreads();   // drain + all waves done before LDS is reused as epilogue scratch

    // ---------------- epilogue: per-row (min, 2nd-min, argmin) over this 128-code tile
    // C/D layout: col = lane&15, row = (lane>>4)*4 + q  [m89]
    float wq[4];
#pragma unroll
    for (int ct = 0; ct < 4; ++ct) wq[ct] = wsq[cb * BK + wc * 64 + ct * 16 + l15];
    const int cbase = cb * BK + wc * 64 + l15;

    float* tm1 = (float*)lds;          // [128][2]  (row-local, wc)
    float* tm2 = tm1 + 256;
    int*   ti1 = (int*)(tm2 + 256);

#pragma unroll
    for (int rt = 0; rt < 4; ++rt) {
        float m1q[4], m2q[4]; int i1q[4];
#pragma unroll
        for (int q = 0; q < 4; ++q) { m1q[q] = INFINITY; m2q[q] = INFINITY; i1q[q] = 0x7fffffff; }
#pragma unroll
        for (int ct = 0; ct < 4; ++ct) {
            const int col = cbase + ct * 16;
#pragma unroll
            for (int q = 0; q < 4; ++q) {
                const float s = fmaf(-2.f, acc[rt][ct][q], wq[ct]);
                if (s < m1q[q]) { m2q[q] = m1q[q]; m1q[q] = s; i1q[q] = col; }
                else if (s < m2q[q]) m2q[q] = s;
            }
        }
#pragma unroll
        for (int msk = 1; msk <= 8; msk <<= 1) {
#pragma unroll
            for (int q = 0; q < 4; ++q) {
                const float om1 = __shfl_xor(m1q[q], msk);
                const float om2 = __shfl_xor(m2q[q], msk);
                const int   oi1 = __shfl_xor(i1q[q], msk);
                if (om1 < m1q[q] || (om1 == m1q[q] && oi1 < i1q[q])) {
                    m2q[q] = fminf(m1q[q], om2); m1q[q] = om1; i1q[q] = oi1;
                } else m2q[q] = fminf(m2q[q], om1);
            }
        }
        if (l15 == 0) {
#pragma unroll
            for (int q = 0; q < 4; ++q) {
                const int rl = wr * 64 + rt * 16 + g * 4 + q;   // row within block
                tm1[rl * 2 + wc] = m1q[q];
                tm2[rl * 2 + wc] = m2q[q];
                ti1[rl * 2 + wc] = i1q[q];
            }
        }
    }
    __syncthreads();
    if (tid < BM) {
        float m1 = tm1[tid * 2], m2 = tm2[tid * 2]; int i1 = ti1[tid * 2];
        const float bm1 = tm1[tid * 2 + 1], bm2 = tm2[tid * 2 + 1]; const int bi = ti1[tid * 2 + 1];
        if (bm1 < m1 || (bm1 == m1 && bi < i1)) { m2 = fminf(m1, bm2); m1 = bm1; i1 = bi; }
        else m2 = fminf(m2, bm1);
        const size_t row = (size_t)rb * BM + tid;
        pm1[row * NCB + cb] = m1;
        pm2[row * NCB + cb] = m2;
        pidx[row * NCB + cb] = i1;
    }
}

// ---------------------------------------------------------------- fallback GEMM (fused cvt) if ws too small
__global__ __launch_bounds__(256, 2) void k_partials(
    const float* __restrict__ A, const float* __restrict__ W,
    const float* __restrict__ wsq,
    float* __restrict__ pm1, float* __restrict__ pm2, int* __restrict__ pidx)
{
    __shared__ __align__(16) ushort lds[2 * BM * KC];
    ushort* As = lds;
    ushort* Ws = lds + BM * KC;

    const int bid = blockIdx.x;
    const int rb = ((bid & 7) << 6) | (bid >> 6);
    const int cb = (bid >> 3) & 7;

    const int tid = threadIdx.x;
    const int wid = tid >> 6, lane = tid & 63;
    const int wr = wid >> 1, wc = wid & 1;
    const int l15 = lane & 15, g = lane >> 4;

    const float* Ab = A + (size_t)rb * BM * DDIM;
    const float* Wb = W + (size_t)cb * BK * DDIM;

    const int srow = tid >> 3;
    const int sk4  = (tid & 7) << 2;
    const int sg   = (tid & 7) >> 1;
    const int sh   = (tid & 1) << 2;

    int aOff[4], bOff[4];
#pragma unroll
    for (int rt = 0; rt < 4; ++rt) {
        const int r = wr * 64 + rt * 16 + l15;
        aOff[rt] = r * KC + ((g ^ ((r >> 1) & 3)) << 3);
        const int c = wc * 64 + rt * 16 + l15;
        bOff[rt] = c * KC + ((g ^ ((c >> 1) & 3)) << 3);
    }

    f32x4 acc[4][4];
#pragma unroll
    for (int rt = 0; rt < 4; ++rt)
#pragma unroll
        for (int ct = 0; ct < 4; ++ct) acc[rt][ct] = (f32x4)0.f;

    float4 av[4], wv[4];
#pragma unroll
    for (int i = 0; i < 4; ++i) {
        av[i] = *(const float4*)(Ab + (size_t)(srow + 32 * i) * DDIM + sk4);
        wv[i] = *(const float4*)(Wb + (size_t)(srow + 32 * i) * DDIM + sk4);
    }

#pragma unroll 1
    for (int ch = 0; ch < NCH; ++ch) {
        __syncthreads();
#pragma unroll
        for (int i = 0; i < 4; ++i) {
            const int r = srow + 32 * i;
            const int wsl = r * KC + ((sg ^ ((r >> 1) & 3)) << 3) + sh;
            ushort4 ua; ua.x = f2h(av[i].x); ua.y = f2h(av[i].y); ua.z = f2h(av[i].z); ua.w = f2h(av[i].w);
            *(ushort4*)(As + wsl) = ua;
            ushort4 uw; uw.x = f2h(wv[i].x); uw.y = f2h(wv[i].y); uw.z = f2h(wv[i].z); uw.w = f2h(wv[i].w);
            *(ushort4*)(Ws + wsl) = uw;
        }
        __syncthreads();
        if (ch + 1 < NCH) {
            const int d0 = (ch + 1) * KC + sk4;
#pragma unroll
            for (int i = 0; i < 4; ++i) {
                av[i] = *(const float4*)(Ab + (size_t)(srow + 32 * i) * DDIM + d0);
                wv[i] = *(const float4*)(Wb + (size_t)(srow + 32 * i) * DDIM + d0);
            }
        }
        half8 af[4], bf[4];
#pragma unroll
        for (int rt = 0; rt < 4; ++rt) af[rt] = *(const half8*)(As + aOff[rt]);
#pragma unroll
        for (int ct = 0; ct < 4; ++ct) bf[ct] = *(const half8*)(Ws + bOff[ct]);
#pragma unroll
        for (int rt = 0; rt < 4; ++rt)
#pragma unroll
            for (int ct = 0; ct < 4; ++ct)
                acc[rt][ct] = __builtin_amdgcn_mfma_f32_16x16x32_f16(af[rt], bf[ct], acc[rt][ct], 0, 0, 0);
    }

    float wq[4];
#pragma unroll
    for (int ct = 0; ct < 4; ++ct) wq[ct] = wsq[cb * BK + wc * 64 + ct * 16 + l15];
    const int cbase = cb * BK + wc * 64 + l15;

    __syncthreads();
    float* tm1 = (float*)lds;
    float* tm2 = tm1 + 256;
    int*   ti1 = (int*)(tm2 + 256);

#pragma unroll
    for (int rt = 0; rt < 4; ++rt) {
        float m1q[4], m2q[4]; int i1q[4];
#pragma unroll
        for (int q = 0; q < 4; ++q) { m1q[q] = INFINITY; m2q[q] = INFINITY; i1q[q] = 0x7fffffff; }
#pragma unroll
        for (int ct = 0; ct < 4; ++ct) {
            const int col = cbase + ct * 16;
#pragma unroll
            for (int q = 0; q < 4; ++q) {
                const float s = fmaf(-2.f, acc[rt][ct][q], wq[ct]);
                if (s < m1q[q]) { m2q[q] = m1q[q]; m1q[q] = s; i1q[q] = col; }
                else if (s < m2q[q]) m2q[q] = s;
            }
        }
#pragma unroll
        for (int msk = 1; msk <= 8; msk <<= 1) {
#pragma unroll
            for (int q = 0; q < 4; ++q) {
                const float om1 = __shfl_xor(m1q[q], msk);
                const float om2 = __shfl_xor(m2q[q], msk);
                const int   oi1 = __shfl_xor(i1q[q], msk);
                if (om1 < m1q[q] || (om1 == m1q[q] && oi1 < i1q[q])) {
                    m2q[q] = fminf(m1q[q], om2); m1q[q] = om1; i1q[q] = oi1;
                } else m2q[q] = fminf(m2q[q], om1);
            }
        }
        if (l15 == 0) {
#pragma unroll
            for (int q = 0; q < 4; ++q) {
                const int rl = wr * 64 + rt * 16 + g * 4 + q;
                tm1[rl * 2 + wc] = m1q[q];
                tm2[rl * 2 + wc] = m2q[q];
                ti1[rl * 2 + wc] = i1q[q];
            }
        }
    }
    __syncthreads();
    if (tid < BM) {
        float m1 = tm1[tid * 2], m2 = tm2[tid * 2]; int i1 = ti1[tid * 2];
        const float bm1 = tm1[tid * 2 + 1], bm2 = tm2[tid * 2 + 1]; const int bi = ti1[tid * 2 + 1];
        if (bm1 < m1 || (bm1 == m1 && bi < i1)) { m2 = fminf(m1, bm2); m1 = bm1; i1 = bi; }
        else m2 = fminf(m2, bm1);
        const size_t row = (size_t)rb * BM + tid;
        pm1[row * NCB + cb] = m1;
        pm2[row * NCB + cb] = m2;
        pidx[row * NCB + cb] = i1;
    }
}

// ---------------------------------------------------------------- merge 8 partials per row
__global__ __launch_bounds__(256) void k_merge(
    const float* __restrict__ pm1, const float* __restrict__ pm2, const int* __restrict__ pidx,
    float* __restrict__ row_s, int* __restrict__ row_idx,
    int* __restrict__ suspects, int* __restrict__ n_suspect)
{
    const int row = blockIdx.x * 256 + threadIdx.x;
    float m1 = INFINITY, m2 = INFINITY; int i1 = 0x7fffffff;
#pragma unroll
    for (int cb = 0; cb < NCB; ++cb) {
        const float bm1 = pm1[(size_t)row * NCB + cb];
        const float bm2 = pm2[(size_t)row * NCB + cb];
        const int   bi  = pidx[(size_t)row * NCB + cb];
        if (bm1 < m1 || (bm1 == m1 && bi < i1)) { m2 = fminf(m1, bm2); m1 = bm1; i1 = bi; }
        else m2 = fminf(m2, bm1);
    }
    row_s[row] = m1;
    row_idx[row] = i1;
    if (m2 - m1 < GAP_TAU) {   // fp16 noise could have reordered: exact re-check
        const int p = atomicAdd(n_suspect, 1);
        suspects[p] = row;
    }
}

// ---------------------------------------------------------------- fp64 re-check of near-ties
__global__ __launch_bounds__(256) void k_repair(
    const float* __restrict__ A, const float* __restrict__ W,
    const float* __restrict__ pm1,
    const int* __restrict__ suspects, const int* __restrict__ n_suspect,
    float* __restrict__ row_s, int* __restrict__ row_idx)
{
    __shared__ __align__(16) float xrow[DDIM];
    __shared__ double wbest[4]; __shared__ int wbi[4];
    __shared__ double xps[4];
    __shared__ int qcb[NCB];
    __shared__ int nq;
    const int ns = *n_suspect;
    const int tid = threadIdx.x;
    const int wid = tid >> 6, lane = tid & 63;
    const int sub = tid & 3;        // 16B stripe within a code
    const int cq  = tid >> 2;       // code slot 0..63

    for (int s = blockIdx.x; s < ns; s += gridDim.x) {
        const int row = suspects[s];
        __syncthreads();   // previous iteration done with shared
        xrow[tid]       = A[(size_t)row * DDIM + tid];
        xrow[tid + 256] = A[(size_t)row * DDIM + tid + 256];
        xrow[tid + 512] = A[(size_t)row * DDIM + tid + 512];
        if (tid == 0) {
            float gmin = INFINITY;
#pragma unroll
            for (int cb = 0; cb < NCB; ++cb) gmin = fminf(gmin, pm1[(size_t)row * NCB + cb]);
            int n = 0;
#pragma unroll
            for (int cb = 0; cb < NCB; ++cb)
                if (pm1[(size_t)row * NCB + cb] <= gmin + FILT_TAU) qcb[n++] = cb;
            nq = n;
        }
        __syncthreads();

        // xsq in fp64 (per-wave stripes combined at the end)
        double xp = 0.0;
        {
            double t;
            t = (double)xrow[tid];       xp = fma(t, t, xp);
            t = (double)xrow[tid + 256]; xp = fma(t, t, xp);
            t = (double)xrow[tid + 512]; xp = fma(t, t, xp);
        }
        xp = waveRedAdd(xp);
        if (lane == 0) xps[wid] = xp;

        double best = 1e300; int bi = 0x7fffffff;
        const int ncand = nq * BK;
        for (int base = 0; base < ncand; base += 64) {
            const int ci = base + cq;
            const bool act = ci < ncand;       // uniform within a quad
            double d = 0.0; int k = 0x7fffffff;
            if (act) {
                k = qcb[ci >> 7] * BK + (ci & (BK - 1));
                const float* wr = W + (size_t)k * DDIM + (sub << 2);
                const float* xr = xrow + (sub << 2);
                double d0 = 0.0, d1 = 0.0;
                for (int i = 0; i < DDIM; i += 16) {
                    const float4 wv = *(const float4*)(wr + i);
                    const float4 xv = *(const float4*)(xr + i);
                    double t;
                    t = (double)xv.x - (double)wv.x; d0 = fma(t, t, d0);
                    t = (double)xv.y - (double)wv.y; d1 = fma(t, t, d1);
                    t = (double)xv.z - (double)wv.z; d0 = fma(t, t, d0);
                    t = (double)xv.w - (double)wv.w; d1 = fma(t, t, d1);
                }
                d = d0 + d1;
            }
            d += __shfl_xor(d, 1);   // combine the 4 stripes of this code
            d += __shfl_xor(d, 2);
            if (act && sub == 0) {
                if (d < best || (d == best && k < bi)) { best = d; bi = k; }
            }
        }
        // wave butterfly (non-leaders hold +inf)
#pragma unroll
        for (int o = 32; o; o >>= 1) {
            const double ob = __shfl_xor(best, o);
            const int oi = __shfl_xor(bi, o);
            if (ob < best || (ob == best && oi < bi)) { best = ob; bi = oi; }
        }
        if (lane == 0) { wbest[wid] = best; wbi[wid] = bi; }
        __syncthreads();
        if (tid == 0) {
            double b = wbest[0]; int i1 = wbi[0];
#pragma unroll
            for (int w = 1; w < 4; ++w)
                if (wbest[w] < b || (wbest[w] == b && wbi[w] < i1)) { b = wbest[w]; i1 = wbi[w]; }
            row_idx[row] = i1;
            row_s[row] = (float)(b - (xps[0] + xps[1] + xps[2] + xps[3]));   // score form (dist - xsq)
        }
    }
}

// ---------------------------------------------------------------- quantize + losses + idx/min_d outputs
// No A re-read: xsq precomputed (convert); commitment error per row == min distance
// (||x-q||^2 = xsq + row_s), and quantized_st == W[idx] (masked) to ulp level.
// Quantized output is streamed with NON-TEMPORAL stores (never re-read; keeps L2 for W).
__global__ __launch_bounds__(256) void k_quantize(
    const float* __restrict__ W,
    const float* __restrict__ xsq,
    const float* __restrict__ row_s, const int* __restrict__ row_idx,
    float* __restrict__ out, float* __restrict__ counts,
    unsigned int* __restrict__ n_valid, double* __restrict__ sum_sqerr)
{
    const int wid = threadIdx.x >> 6, lane = threadIdx.x & 63;
    __shared__ double s_sum[4];
    __shared__ unsigned s_val[4];
    double wsum = 0.0; unsigned wval = 0;

#pragma unroll 1
    for (int it = 0; it < NROWS / (QGRID * 4); ++it) {
        const int row = (it * QGRID + blockIdx.x) * 4 + wid;
        const float xs = xsq[row];
        const bool valid = xs > 1e-12f;            // norm > 1e-6
        const int idx = row_idx[row];
        const int idxm = valid ? idx : 0;
        const float maskf = valid ? 1.f : 0.f;
        const float* w = W + (size_t)idx * DDIM;
        float* oq = out + (size_t)row * DDIM;
#pragma unroll
        for (int j = 0; j < 3; ++j) {
            const float4 wv = *(const float4*)(w + (lane + 64 * j) * 4);
            nt_store4(oq + (lane + 64 * j) * 4,
                      wv.x * maskf, wv.y * maskf, wv.z * maskf, wv.w * maskf);
        }
        if (lane == 0) {
            const float mind = xs + row_s[row];
            if (valid) {
                wsum += (double)mind;
                ++wval;
                atomicAdd(&counts[idxm], 1.0f);
            }
            out[OUT_IDX + row]  = (float)idxm;
            out[OUT_MIND + row] = valid ? mind : 0.f;
        }
    }

    if (lane == 0) { s_sum[wid] = wsum; s_val[wid] = wval; }
    __syncthreads();
    if (threadIdx.x == 0) {
        atomicAdd(sum_sqerr, s_sum[0] + s_sum[1] + s_sum[2] + s_sum[3]);
        atomicAdd(n_valid, s_val[0] + s_val[1] + s_val[2] + s_val[3]);
    }
}

// ---------------------------------------------------------------- scalar losses
__global__ __launch_bounds__(256) void k_final(
    const float* __restrict__ counts, const unsigned int* __restrict__ n_valid,
    const double* __restrict__ sum_sqerr, float* __restrict__ out)
{
    const int t = threadIdx.x;
    const float nv = (float)(*n_valid);
    double ent = 0.0;
    for (int k = t; k < KCODES; k += 256) {
        const float p = counts[k] / nv;
        ent += (double)(p * logf(p + 1e-10f));
    }
    ent = waveRedAdd(ent);
    __shared__ double ps[4];
    if ((t & 63) == 0) ps[t >> 6] = ent;
    __syncthreads();
    if (t == 0) {
        const double e = ps[0] + ps[1] + ps[2] + ps[3];
        const double perp = exp(-e);
        const double ploss = -log(perp + 1e-10);
        const double commit = *sum_sqerr / ((double)(*n_valid) * (double)DDIM);
        out[OUT_LOSS] = (float)(0.25 * commit + 0.1 * ploss);
        out[OUT_PERP] = (float)perp;
    }
}

// ----------------------------------------------------------------
extern "C" void kernel_launch(void* const* d_in, const int* in_sizes, int n_in,
                              void* d_out, int out_size, void* d_ws, size_t ws_size,
                              hipStream_t stream) {
    const float* A = (const float*)d_in[0];   // [65536, 768]
    const float* W = (const float*)d_in[1];   // [1024, 768]
    float* out = (float*)d_out;
    char* ws = (char*)d_ws;
    if (ws_size < (size_t)WS_END) return;     // needs >=7 MB scratch

    double*   sum_sqerr = (double*)(ws + WS_SUM);
    int*      n_suspect = (int*)(ws + WS_NSUS);
    unsigned* n_valid   = (unsigned*)(ws + WS_NVAL);
    float*    counts    = (float*)(ws + WS_COUNTS);
    float*    wsq       = (float*)(ws + WS_WSQ);
    float*    xsq       = (float*)(ws + WS_XSQ);
    float*    row_s     = (float*)(ws + WS_ROWS);
    int*      row_idx   = (int*)(ws + WS_ROWI);
    int*      suspects  = (int*)(ws + WS_SUSP);
    float*    pm1       = (float*)(ws + WS_PM1);
    float*    pm2       = (float*)(ws + WS_PM2);
    int*      pidx      = (int*)(ws + WS_PIDX);
    ushort*   Af16      = (ushort*)(ws + WS_AF16);
    ushort*   Wf16      = (ushort*)(ws + WS_WF16);

    const bool big = ws_size >= (size_t)WS_END2;   // ~105 MB: fp16-preconvert path

    hipLaunchKernelGGL(k_wsq, dim3(KCODES), dim3(256), 0, stream, W, wsq, counts, n_suspect, n_valid, sum_sqerr);
    if (big) {
        hipLaunchKernelGGL(k_convert, dim3(2048), dim3(192), 0, stream, A, W, Af16, Wf16, xsq);
        hipLaunchKernelGGL(k_partials_g, dim3((NROWS / BM) * NCB), dim3(256), 0, stream, Af16, Wf16, wsq, pm1, pm2, pidx);
    } else {
        hipLaunchKernelGGL(k_xsq, dim3(NROWS / 4), dim3(256), 0, stream, A, xsq);
        hipLaunchKernelGGL(k_partials, dim3((NROWS / BM) * NCB), dim3(256), 0, stream, A, W, wsq, pm1, pm2, pidx);
    }
    hipLaunchKernelGGL(k_merge, dim3(NROWS / 256), dim3(256), 0, stream, pm1, pm2, pidx, row_s, row_idx, suspects, n_suspect);
    hipLaunchKernelGGL(k_repair, dim3(RGRID), dim3(256), 0, stream, A, W, pm1, suspects, n_suspect, row_s, row_idx);
    hipLaunchKernelGGL(k_quantize, dim3(QGRID), dim3(256), 0, stream, W, xsq, row_s, row_idx, out, counts, n_valid, sum_sqerr);
    hipLaunchKernelGGL(k_final, dim3(1), dim3(256), 0, stream, counts, n_valid, sum_sqerr, out);
}